// Round 5
// baseline (275.734 us; speedup 1.0000x reference)
//
#include <hip/hip_runtime.h>

// LovaszSoftmaxLoss B=8, C=21, H=W=512 — sort-free counting-sort formulation.
// loss = sum_i e_i*(g_i - g_{i-1}) over descending-sorted errors; equal-key
// runs contribute e*(g(b)-g(a-1)) independent of tie order, so a histogram
// over quantized keys suffices. Key = 12 octaves x 6 mantissa bits = 768 bins
// (bin-center rel error 0.78% vs 2% threshold).
//
// R4 post-mortem: timed window carries ~210us of fixed harness overhead
// (704MB ws poison + input restore); our kernels are ~55us. Remaining fat is
// the 66MB partial-histogram round trip. R5: k_fused merges its LDS hist
// directly into a 1MB L2-resident global u64 histogram via sparse atomics
// (only nonzero bins); k_scan loads it directly. No partial buffer.

#define NB    8
#define NC    21
#define NPIX  262144
#define NROWS (NB * NC)      // 168
#define NBINS 768            // key = (fexp+12)<<6 | mant6 ; fexp in [-12,0]
#define BPB   64             // blocks per batch
#define CHUNK (NPIX / BPB)   // 4096 pixels per block

// ---------------- Fused kernel: softmax -> error -> LDS hist -> global merge ----------------
// 512 threads, 8 pixels/thread. Per-block count<=8192 (14b), labelsum<=163840 (18b).
__global__ __launch_bounds__(512, 4) void k_fused(
    const float* __restrict__ x,
    const int* __restrict__ tgt,
    unsigned long long* __restrict__ ghist) {
  __shared__ unsigned hist[NC * NBINS];      // 63 KB
  int tid = threadIdx.x;
  for (int i = tid; i < NC * NBINS; i += 512) hist[i] = 0;
  __syncthreads();

  int b     = blockIdx.x >> 6;
  int chunk = blockIdx.x & 63;
  const float* xb = x + (size_t)b * NC * NPIX + (size_t)chunk * CHUNK;
  const int*   tb = tgt + (size_t)b * NPIX + (size_t)chunk * CHUNK;

  #pragma unroll
  for (int g = 0; g < 2; ++g) {
    int n4 = (g * 512 + tid) * 4;            // 0..4092, coalesced float4

    float v[NC][4];
    float m[4] = {-3.4e38f, -3.4e38f, -3.4e38f, -3.4e38f};
    #pragma unroll
    for (int c = 0; c < NC; ++c) {
      float4 t = *(const float4*)(xb + (size_t)c * NPIX + n4);
      v[c][0] = t.x; v[c][1] = t.y; v[c][2] = t.z; v[c][3] = t.w;
      m[0] = fmaxf(m[0], t.x); m[1] = fmaxf(m[1], t.y);
      m[2] = fmaxf(m[2], t.z); m[3] = fmaxf(m[3], t.w);
    }
    float Z[4] = {0.f, 0.f, 0.f, 0.f};
    #pragma unroll
    for (int c = 0; c < NC; ++c) {
      #pragma unroll
      for (int j = 0; j < 4; ++j) {
        v[c][j] = __expf(v[c][j] - m[j]);
        Z[j] += v[c][j];
      }
    }
    float iZ[4];
    #pragma unroll
    for (int j = 0; j < 4; ++j) iZ[j] = 1.0f / Z[j];

    int4 tv = *(const int4*)(tb + n4);
    int tl[4] = {tv.x, tv.y, tv.z, tv.w};

    #pragma unroll
    for (int c = 0; c < NC; ++c) {
      unsigned* hr = hist + c * NBINS;
      #pragma unroll
      for (int j = 0; j < 4; ++j) {
        float p = v[c][j] * iZ[j];
        float e = fabsf(((c == tl[j]) ? 1.0f : 0.0f) - p);   // e in [0,1]
        unsigned fb   = __float_as_uint(e);
        int      fexp = (int)(fb >> 23) - 127;
        unsigned key;
        if (fexp < -12) key = 0u;
        else {
          key = (((unsigned)(fexp + 12)) << 6) | ((fb >> 17) & 63u);
          if (key > NBINS - 1) key = NBINS - 1;              // e==1.0 / safety
        }
        atomicAdd(hr + key, (1u << 18) | (unsigned)tl[j]);
      }
    }
  }
  __syncthreads();

  // sparse merge into L2-resident global u64 hist[b][c][bin]
  unsigned long long* gh = ghist + (size_t)b * NC * NBINS;
  for (int i = tid; i < NC * NBINS; i += 512) {
    unsigned v = hist[i];
    if (v)
      atomicAdd(gh + i,
                ((unsigned long long)(v >> 18) << 32) | (unsigned long long)(v & 0x3FFFFu));
  }
}

// ---------------- u64 shuffle helpers ----------------
__device__ inline unsigned long long shfl_up_u64(unsigned long long v, int off) {
  unsigned lo = (unsigned)v, hi = (unsigned)(v >> 32);
  lo = (unsigned)__shfl_up((int)lo, off, 64);
  hi = (unsigned)__shfl_up((int)hi, off, 64);
  return ((unsigned long long)hi << 32) | lo;
}
__device__ inline unsigned long long shfl_down_u64(unsigned long long v, int off) {
  unsigned lo = (unsigned)v, hi = (unsigned)(v >> 32);
  lo = (unsigned)__shfl_down((int)lo, off, 64);
  hi = (unsigned)__shfl_down((int)hi, off, 64);
  return ((unsigned long long)hi << 32) | lo;
}

// ---------------- Scan kernel: descending scan over 768 bins per row ----------------
// 168 blocks x 768 threads (12 waves); one thread per bin. row = b*NC + c.
__global__ __launch_bounds__(768) void k_scan(
    const unsigned long long* __restrict__ ghist,
    float* __restrict__ out) {
  int row  = blockIdx.x;                     // 0..167
  int tid  = threadIdx.x;                    // == bin slot
  int lane = tid & 63;
  int wave = tid >> 6;                       // 12 waves

  __shared__ unsigned long long hist0[NBINS];   // 6 KB
  __shared__ unsigned long long wtot[12];
  __shared__ double wred[12];
  __shared__ double sT;

  hist0[tid] = ghist[(size_t)row * NBINS + tid];
  __syncthreads();

  // total labelsum T (exact; fields can't overflow: cnt<=262144, ls<=5.3M)
  unsigned long long tot = hist0[tid];
  #pragma unroll
  for (int off = 32; off > 0; off >>= 1) tot += shfl_down_u64(tot, off);
  if (lane == 0) wtot[wave] = tot;
  __syncthreads();
  if (tid == 0) {
    unsigned long long g = 0;
    #pragma unroll
    for (int w = 0; w < 12; ++w) g += wtot[w];
    sT = (double)(unsigned)(g & 0xffffffffULL);
  }
  __syncthreads();
  double T = sT;
  __syncthreads();

  // single-chunk descending scan over 768 bins
  int bin = (NBINS - 1) - tid;
  unsigned long long v = hist0[bin];

  unsigned long long s = v;                  // intra-wave inclusive scan
  #pragma unroll
  for (int off = 1; off < 64; off <<= 1) {
    unsigned long long u = shfl_up_u64(s, off);
    if (lane >= off) s += u;
  }
  if (lane == 63) wtot[wave] = s;
  __syncthreads();

  unsigned long long woff = 0;
  for (int w = 0; w < wave; ++w) woff += wtot[w];
  unsigned long long excl = s - v + woff;    // strictly-greater prefix

  double acc = 0.0;
  unsigned n = (unsigned)(v >> 32);
  if (n) {
    unsigned sl = (unsigned)(v & 0xffffffffu);
    unsigned cb = (unsigned)(excl >> 32);
    unsigned sb = (unsigned)(excl & 0xffffffffu);
    double Sb = (double)sb + (double)sl;
    double gb = 1.0 - (T - Sb) / (T + (double)(cb + n) - Sb);
    double ga = (cb == 0) ? 0.0
                          : 1.0 - (T - (double)sb) / (T + (double)cb - (double)sb);
    unsigned key = (unsigned)bin;
    unsigned ex  = key >> 6, mant = key & 63u;
    float e = ldexpf(1.0f + ((float)mant + 0.5f) * 0.015625f, (int)ex - 12);
    acc = (double)e * (gb - ga);
  }

  // block reduce acc (12 waves)
  #pragma unroll
  for (int off = 32; off > 0; off >>= 1) acc += __shfl_down(acc, off, 64);
  if (lane == 0) wred[wave] = acc;
  __syncthreads();
  if (tid == 0) {
    double ssum = 0.0;
    #pragma unroll
    for (int w = 0; w < 12; ++w) ssum += wred[w];
    atomicAdd(out, (float)(ssum * (1.0 / (double)NROWS)));
  }
}

extern "C" void kernel_launch(void* const* d_in, const int* in_sizes, int n_in,
                              void* d_out, int out_size, void* d_ws, size_t ws_size,
                              hipStream_t stream) {
  const float* x  = (const float*)d_in[0];   // (B, C, H, W) float32
  const int* tgt  = (const int*)d_in[1];     // (B, H, W) int32
  float* out      = (float*)d_out;
  unsigned long long* ghist = (unsigned long long*)d_ws;  // 168*768*8 = 1.03 MB

  hipMemsetAsync(d_ws, 0, (size_t)NROWS * NBINS * sizeof(unsigned long long), stream);
  hipMemsetAsync(d_out, 0, sizeof(float), stream);

  k_fused<<<NB * BPB, 512, 0, stream>>>(x, tgt, ghist);
  k_scan<<<NROWS, NBINS, 0, stream>>>(ghist, out);
}